// Round 2
// 1046.636 us; speedup vs baseline: 1.1010x; 1.1010x over previous
//
#include <hip/hip_runtime.h>
#include <math.h>

#define NN 500000
#define NE 1000000
#define OPC 5000
#define NBLK_SCAN 489
#define NBLK ((NN + 127) / 128)   // 3907

typedef short short8 __attribute__((ext_vector_type(8)));
typedef float f32x4 __attribute__((ext_vector_type(4)));

static __device__ __forceinline__ short f2bf(float f) {
    unsigned u = __builtin_bit_cast(unsigned, f);
    u += 0x7fffu + ((u >> 16) & 1u);
    return (short)(u >> 16);
}
static __device__ __forceinline__ float bf2f(short s) {
    unsigned u = ((unsigned)(unsigned short)s) << 16;
    return __builtin_bit_cast(float, u);
}
static __device__ __forceinline__ short8 cvt8(float4 a, float4 b) {
    short8 r;
    r[0] = f2bf(a.x); r[1] = f2bf(a.y); r[2] = f2bf(a.z); r[3] = f2bf(a.w);
    r[4] = f2bf(b.x); r[5] = f2bf(b.y); r[6] = f2bf(b.z); r[7] = f2bf(b.w);
    return r;
}
static __device__ __forceinline__ short8 ldcvt(const float* p) {
    const float4* p4 = (const float4*)p;
    return cvt8(p4[0], p4[1]);
}

// ---------------- prep: weights -> bf16, [col][k] rows, XOR-swizzled LDS images ----------
__global__ void prep_kernel(const float* __restrict__ W1, const float* __restrict__ W2,
                            const float* __restrict__ Wself, const float* __restrict__ Wagg,
                            const float* __restrict__ muW, const float* __restrict__ lvW,
                            short* __restrict__ W1s, short* __restrict__ W2s,
                            short* __restrict__ Wds0, short* __restrict__ Wds1,
                            short* __restrict__ HWp)
{
    int idx = blockIdx.x * 256 + threadIdx.x;   // up to 32768
    {   // W1s: idx = col*256 + c'*8 + j
        int col = idx >> 8, r = idx & 255;
        int k = ((r >> 3) ^ (col & 7)) * 8 + (r & 7);
        W1s[idx] = (k < 200) ? f2bf(W1[k * 128 + col]) : (short)0;
    }
    {   // W2s: idx = col*128 + c'*8 + j  (col 0..255)
        int col = idx >> 7, r = idx & 127;
        int k = ((r >> 3) ^ (col & 7)) * 8 + (r & 7);
        W2s[idx] = f2bf(W2[k * 256 + col]);
    }
    if (idx < 128 * 128) {  // Wds0/1
        int col = idx >> 7, r = idx & 127;
        int k = ((r >> 3) ^ (col & 7)) * 8 + (r & 7);
        Wds0[idx] = f2bf(Wself[k * 128 + col]);
        Wds1[idx] = f2bf(Wagg[k * 128 + col]);
    }
    if (idx < 16 * 128) {
        int n = idx >> 7, k = idx & 127;
        HWp[idx] = (n < 8) ? f2bf(muW[k * 8 + n]) : f2bf(lvW[k * 8 + (n - 8)]);
    }
}

// ---------------- enc1: h = relu(feats @ W1 + b1) ----------------
__global__ __launch_bounds__(256, 2) void enc1_mfma(
    const int* __restrict__ op_id, const int* __restrict__ sv_id, const int* __restrict__ st_id,
    const float* __restrict__ lat,
    const float* __restrict__ opE, const float* __restrict__ svE, const float* __restrict__ stE,
    const short* __restrict__ W1s, const float* __restrict__ b1,
    short* __restrict__ h_bf)
{
    __shared__ __align__(16) short Bb[128 * 256];   // 64 KB swizzled W1; reused as h-stage
    const int tid = threadIdx.x;
    const int lane = tid & 63, w = tid >> 6;
    const int m = lane & 15, q = lane >> 4;
    const int bbase = blockIdx.x * 128;
    const int wbase = bbase + w * 32;
    const bool wv = (wbase < NN);

    {   // identity copy 64KB (pre-swizzled image)
        const short8* g = (const short8*)W1s;
        short8* l = (short8*)Bb;
        #pragma unroll
        for (int i = 0; i < 16; i++) l[tid + 256 * i] = g[tid + 256 * i];
    }
    __syncthreads();

    f32x4 acc[2][8];
    #pragma unroll
    for (int a2 = 0; a2 < 2; a2++)
        #pragma unroll
        for (int nf = 0; nf < 8; nf++) acc[a2][nf] = (f32x4)0.0f;

    if (wv) {
        const int n0 = wbase + m, n1 = wbase + 16 + m;
        const size_t op0 = (size_t)op_id[n0] * 64, op1 = (size_t)op_id[n1] * 64;
        const size_t sv0 = (size_t)sv_id[n0] * 64, sv1 = (size_t)sv_id[n1] * 64;
        const size_t st0 = (size_t)st_id[n0] * 64, st1 = (size_t)st_id[n1] * 64;

        #pragma unroll
        for (int s = 0; s < 7; s++) {
            short8 a0, a1;
            if (s < 2) {
                a0 = ldcvt(opE + op0 + s * 32 + q * 8);
                a1 = ldcvt(opE + op1 + s * 32 + q * 8);
            } else if (s < 4) {
                a0 = ldcvt(svE + sv0 + (s - 2) * 32 + q * 8);
                a1 = ldcvt(svE + sv1 + (s - 2) * 32 + q * 8);
            } else if (s < 6) {
                a0 = ldcvt(stE + st0 + (s - 4) * 32 + q * 8);
                a1 = ldcvt(stE + st1 + (s - 4) * 32 + q * 8);
            } else {
                if (q == 0) {
                    a0 = ldcvt(lat + (size_t)n0 * 8);
                    a1 = ldcvt(lat + (size_t)n1 * 8);
                } else {
                    #pragma unroll
                    for (int i = 0; i < 8; i++) { a0[i] = 0; a1[i] = 0; }
                }
            }
            const int slot = ((4 * s + q) ^ (m & 7)) * 8;
            #pragma unroll
            for (int nf = 0; nf < 8; nf++) {
                const short8 b = *(const short8*)&Bb[(nf * 16 + m) * 256 + slot];
                acc[0][nf] = __builtin_amdgcn_mfma_f32_16x16x32_bf16(a0, b, acc[0][nf], 0, 0, 0);
                acc[1][nf] = __builtin_amdgcn_mfma_f32_16x16x32_bf16(a1, b, acc[1][nf], 0, 0, 0);
            }
        }
    }
    __syncthreads();   // all B-reads done; Bb now reusable as h-stage [128][136]

    if (wv) {
        #pragma unroll
        for (int nf = 0; nf < 8; nf++) {
            int col = nf * 16 + m;
            float bb = b1[col];
            #pragma unroll
            for (int a2 = 0; a2 < 2; a2++)
                #pragma unroll
                for (int r = 0; r < 4; r++) {
                    int g = w * 32 + a2 * 16 + q * 4 + r;
                    Bb[g * 136 + col] = f2bf(fmaxf(acc[a2][nf][r] + bb, 0.0f));
                }
        }
    }
    __syncthreads();

    {   // vectorized store: thread t owns 64 consecutive cols of one row
        int g = tid >> 1, cb = (tid & 1) * 64;
        int node = bbase + g;
        if (node < NN) {
            short8* dst = (short8*)(h_bf + (size_t)node * 128 + cb);
            const short8* src = (const short8*)&Bb[g * 136 + cb];
            #pragma unroll
            for (int i = 0; i < 8; i++) dst[i] = src[i];
        }
    }
}

// ---------------- enc2: y=h@W2+b2; z=mu+exp(.5*tanh(lv))*eps; KL ----------------
__global__ __launch_bounds__(256, 2) void enc2_mfma(
    const short* __restrict__ h_bf, const short* __restrict__ W2s, const float* __restrict__ b2,
    const float* __restrict__ eps, short* __restrict__ z_bf, float* __restrict__ kl_sum)
{
    __shared__ __align__(16) short Bb[256 * 128];   // 64 KB swizzled W2; reused as (mu,s) stage
    int* ldsI = (int*)Bb;                           // [64][132] ints per a2-pass (33792 B)
    const int tid = threadIdx.x;
    const int lane = tid & 63, w = tid >> 6;
    const int m = lane & 15, q = lane >> 4;
    const int bbase = blockIdx.x * 128;
    const int wbase = bbase + w * 32;
    const bool wv = (wbase < NN);

    {
        const short8* g8 = (const short8*)W2s;
        short8* l = (short8*)Bb;
        #pragma unroll
        for (int i = 0; i < 16; i++) l[tid + 256 * i] = g8[tid + 256 * i];
    }
    __syncthreads();

    f32x4 acc[2][16];
    #pragma unroll
    for (int a2 = 0; a2 < 2; a2++)
        #pragma unroll
        for (int nf = 0; nf < 16; nf++) acc[a2][nf] = (f32x4)0.0f;

    if (wv) {
        short8 a[2][4];
        #pragma unroll
        for (int s = 0; s < 4; s++) {
            a[0][s] = *(const short8*)(h_bf + (size_t)(wbase + m) * 128 + s * 32 + q * 8);
            a[1][s] = *(const short8*)(h_bf + (size_t)(wbase + 16 + m) * 128 + s * 32 + q * 8);
        }
        #pragma unroll
        for (int s = 0; s < 4; s++) {
            const int slot = ((4 * s + q) ^ (m & 7)) * 8;
            #pragma unroll
            for (int nf = 0; nf < 16; nf++) {
                const short8 b = *(const short8*)&Bb[(nf * 16 + m) * 128 + slot];
                acc[0][nf] = __builtin_amdgcn_mfma_f32_16x16x32_bf16(a[0][s], b, acc[0][nf], 0, 0, 0);
                acc[1][nf] = __builtin_amdgcn_mfma_f32_16x16x32_bf16(a[1][s], b, acc[1][nf], 0, 0, 0);
            }
        }
    }
    __syncthreads();   // B-reads done; Bb reusable

    float kll = 0.0f;
    #pragma unroll
    for (int a2 = 0; a2 < 2; a2++) {
        if (wv) {
            #pragma unroll
            for (int nf = 0; nf < 8; nf++) {
                int col = nf * 16 + m;
                float bm = b2[col], bl = b2[col + 128];
                #pragma unroll
                for (int r = 0; r < 4; r++) {
                    float mu = acc[a2][nf][r] + bm;
                    float lr = acc[a2][nf + 8][r] + bl;
                    // tanh via rcp: 1 - 2/(e^{2x}+1); saturates correctly at +-inf
                    float e2 = __expf(2.0f * lr);
                    float t  = 1.0f - 2.0f * __builtin_amdgcn_rcpf(e2 + 1.0f);
                    float s  = __expf(0.5f * t);          // e^{lv} = s*s
                    kll += t + 1.0f - s * s - mu * mu;
                    int pk = (int)(unsigned short)f2bf(mu)
                           | ((int)(unsigned short)f2bf(s) << 16);
                    ldsI[(w * 16 + q * 4 + r) * 132 + col] = pk;
                }
            }
        }
        __syncthreads();
        {   // vectorized fuse: thread t owns 32 consecutive cols of one row
            int g = tid >> 2, cb = (tid & 3) * 32;
            int node = bbase + (g >> 4) * 32 + a2 * 16 + (g & 15);
            if (node < NN) {
                const float4* ep = (const float4*)(eps + (size_t)node * 128 + cb);
                const int4*   lp = (const int4*)&ldsI[g * 132 + cb];
                #pragma unroll
                for (int c = 0; c < 4; c++) {
                    int4 va = lp[c * 2], vb = lp[c * 2 + 1];
                    float4 ea = ep[c * 2], eb = ep[c * 2 + 1];
                    short8 o;
                    o[0] = f2bf(fmaf(bf2f((short)(va.x >> 16)), ea.x, bf2f((short)va.x)));
                    o[1] = f2bf(fmaf(bf2f((short)(va.y >> 16)), ea.y, bf2f((short)va.y)));
                    o[2] = f2bf(fmaf(bf2f((short)(va.z >> 16)), ea.z, bf2f((short)va.z)));
                    o[3] = f2bf(fmaf(bf2f((short)(va.w >> 16)), ea.w, bf2f((short)va.w)));
                    o[4] = f2bf(fmaf(bf2f((short)(vb.x >> 16)), eb.x, bf2f((short)vb.x)));
                    o[5] = f2bf(fmaf(bf2f((short)(vb.y >> 16)), eb.y, bf2f((short)vb.y)));
                    o[6] = f2bf(fmaf(bf2f((short)(vb.z >> 16)), eb.z, bf2f((short)vb.z)));
                    o[7] = f2bf(fmaf(bf2f((short)(vb.w >> 16)), eb.w, bf2f((short)vb.w)));
                    *(short8*)(z_bf + (size_t)node * 128 + cb + c * 8) = o;
                }
            }
        }
        __syncthreads();
    }
    #pragma unroll
    for (int off = 32; off > 0; off >>= 1) kll += __shfl_down(kll, off);
    if (lane == 0) atomicAdd(kl_sum, kll);
}

// ---------------- CSR build ----------------
__global__ void hist_kernel(const int* __restrict__ edst, int* __restrict__ cnt)
{
    int e = blockIdx.x * 256 + threadIdx.x;
    if (e < NE) atomicAdd(&cnt[edst[e]], 1);
}

__global__ void scan1_kernel(const int* __restrict__ cnt, int* __restrict__ bsum)
{
    __shared__ int ls[256];
    int b = blockIdx.x, tid = threadIdx.x;
    int idx0 = b * 1024 + tid * 4;
    int s = 0;
    #pragma unroll
    for (int i = 0; i < 4; i++) { int idx = idx0 + i; if (idx < NN) s += cnt[idx]; }
    ls[tid] = s; __syncthreads();
    for (int off = 128; off > 0; off >>= 1) {
        if (tid < off) ls[tid] += ls[tid + off];
        __syncthreads();
    }
    if (tid == 0) bsum[b] = ls[0];
}

__global__ void scan2_kernel(int* __restrict__ bsum, int* __restrict__ rowstart)
{
    __shared__ int ls[512];
    int tid = threadIdx.x;
    int v = (tid < NBLK_SCAN) ? bsum[tid] : 0;
    ls[tid] = v; __syncthreads();
    for (int off = 1; off < 512; off <<= 1) {
        int t = 0;
        if (tid >= off) t = ls[tid - off];
        __syncthreads();
        ls[tid] += t;
        __syncthreads();
    }
    if (tid < NBLK_SCAN) bsum[tid] = (tid == 0) ? 0 : ls[tid - 1];
    if (tid == 0) rowstart[NN] = NE;
}

__global__ void scan3_kernel(const int* __restrict__ cnt, const int* __restrict__ bsum,
                             int* __restrict__ rowstart, int* __restrict__ cursor)
{
    __shared__ int ls[256];
    int b = blockIdx.x, tid = threadIdx.x;
    int idx0 = b * 1024 + tid * 4;
    int v[4]; int s = 0;
    #pragma unroll
    for (int i = 0; i < 4; i++) { int idx = idx0 + i; v[i] = (idx < NN) ? cnt[idx] : 0; s += v[i]; }
    ls[tid] = s; __syncthreads();
    for (int off = 1; off < 256; off <<= 1) {
        int t = 0;
        if (tid >= off) t = ls[tid - off];
        __syncthreads();
        ls[tid] += t;
        __syncthreads();
    }
    int ex = ls[tid] - s + bsum[b];
    #pragma unroll
    for (int i = 0; i < 4; i++) {
        int idx = idx0 + i;
        if (idx < NN) { rowstart[idx] = ex; cursor[idx] = ex; }
        ex += v[i];
    }
}

__global__ void fill_kernel(const int* __restrict__ esrc, const int* __restrict__ edst,
                            int* __restrict__ cursor, int* __restrict__ csr)
{
    int e = blockIdx.x * 256 + threadIdx.x;
    if (e < NE) {
        int pos = atomicAdd(&cursor[edst[e]], 1);
        csr[pos] = esrc[e];
    }
}

// ---------------- dec: fused gather + dual GEMM + MFMA heads + loss ----------------
__global__ __launch_bounds__(256, 2) void dec_mfma(
    const short* __restrict__ z_bf, const int* __restrict__ rowstart, const int* __restrict__ csr,
    const short* __restrict__ Wds0, const short* __restrict__ Wds1, const short* __restrict__ HWp,
    const float* __restrict__ mub, const float* __restrict__ lvb,
    const float* __restrict__ opwise, const int* __restrict__ op_id,
    const float* __restrict__ lat,
    float* __restrict__ op_loss, float* __restrict__ op_cnt,
    float* __restrict__ loss_sum)
{
    __shared__ __align__(16) short regionA[128 * 128];   // 32 KB: agg (swizzled) -> yd (swizzled)
    __shared__ __align__(16) char  regionB[32768];       // Wself -> Wagg -> {hw | mlv}
    short* Bb  = (short*)regionB;
    short* hw  = (short*)regionB;                        // [16][136] after GEMM
    float* mlv = (float*)(regionB + 4608);               // [128][16]

    const int tid = threadIdx.x;
    const int lane = tid & 63, w = tid >> 6;
    const int m = lane & 15, q = lane >> 4;
    const int bbase = blockIdx.x * 128;
    const int wbase = bbase + w * 32;
    const bool wv = (wbase < NN);

    // ---- gather agg tile into regionA (swizzled) + stage Wself into Bb ----
    {
        const short8* g = (const short8*)Wds0;
        short8* l = (short8*)Bb;
        #pragma unroll
        for (int i = 0; i < 8; i++) l[tid + 256 * i] = g[tid + 256 * i];
    }
    {
        int nodeL = tid & 127, hh = tid >> 7;
        int n = bbase + nodeL;
        float a[64];
        #pragma unroll
        for (int i = 0; i < 64; i++) a[i] = 0.0f;
        if (n < NN) {
            int r0 = rowstart[n], r1 = rowstart[n + 1];
            for (int e = r0; e < r1; e++) {
                const short8* zp = (const short8*)(z_bf + (size_t)csr[e] * 128 + hh * 64);
                #pragma unroll
                for (int j = 0; j < 8; j++) {
                    short8 v = zp[j];
                    #pragma unroll
                    for (int i = 0; i < 8; i++) a[j * 8 + i] += bf2f(v[i]);
                }
            }
        }
        #pragma unroll
        for (int j = 0; j < 8; j++) {
            int slot = ((hh * 8 + j) ^ (nodeL & 7)) * 8;
            short8 o;
            #pragma unroll
            for (int i = 0; i < 8; i++) o[i] = f2bf(a[j * 8 + i]);
            *(short8*)&regionA[nodeL * 128 + slot] = o;
        }
    }
    __syncthreads();

    f32x4 acc[2][8];
    #pragma unroll
    for (int a2 = 0; a2 < 2; a2++)
        #pragma unroll
        for (int nf = 0; nf < 8; nf++) acc[a2][nf] = (f32x4)0.0f;

    // ---- phase 1: z @ Wself ----
    if (wv) {
        short8 az[2][4];
        #pragma unroll
        for (int s = 0; s < 4; s++) {
            az[0][s] = *(const short8*)(z_bf + (size_t)(wbase + m) * 128 + s * 32 + q * 8);
            az[1][s] = *(const short8*)(z_bf + (size_t)(wbase + 16 + m) * 128 + s * 32 + q * 8);
        }
        #pragma unroll
        for (int s = 0; s < 4; s++) {
            const int slot = ((4 * s + q) ^ (m & 7)) * 8;
            #pragma unroll
            for (int nf = 0; nf < 8; nf++) {
                const short8 b = *(const short8*)&Bb[(nf * 16 + m) * 128 + slot];
                acc[0][nf] = __builtin_amdgcn_mfma_f32_16x16x32_bf16(az[0][s], b, acc[0][nf], 0, 0, 0);
                acc[1][nf] = __builtin_amdgcn_mfma_f32_16x16x32_bf16(az[1][s], b, acc[1][nf], 0, 0, 0);
            }
        }
    }
    __syncthreads();

    // ---- stage Wagg ----
    {
        const short8* g = (const short8*)Wds1;
        short8* l = (short8*)Bb;
        #pragma unroll
        for (int i = 0; i < 8; i++) l[tid + 256 * i] = g[tid + 256 * i];
    }
    __syncthreads();

    // ---- phase 2: agg @ Wagg (A from regionA, swizzled) ----
    if (wv) {
        #pragma unroll
        for (int s = 0; s < 4; s++) {
            const int slot = ((4 * s + q) ^ (m & 7)) * 8;
            const short8 a0 = *(const short8*)&regionA[(w * 32 + m) * 128 + slot];
            const short8 a1 = *(const short8*)&regionA[(w * 32 + 16 + m) * 128 + slot];
            #pragma unroll
            for (int nf = 0; nf < 8; nf++) {
                const short8 b = *(const short8*)&Bb[(nf * 16 + m) * 128 + slot];
                acc[0][nf] = __builtin_amdgcn_mfma_f32_16x16x32_bf16(a0, b, acc[0][nf], 0, 0, 0);
                acc[1][nf] = __builtin_amdgcn_mfma_f32_16x16x32_bf16(a1, b, acc[1][nf], 0, 0, 0);
            }
        }
    }
    __syncthreads();

    // ---- yd = relu(acc) -> regionA (swizzled); stage head weights ----
    if (wv) {
        #pragma unroll
        for (int a2 = 0; a2 < 2; a2++)
            #pragma unroll
            for (int nf = 0; nf < 8; nf++) {
                int c = nf * 2 + (m >> 3);
                #pragma unroll
                for (int r = 0; r < 4; r++) {
                    int node = w * 32 + a2 * 16 + q * 4 + r;
                    regionA[node * 128 + ((c ^ (node & 7)) * 8) + (m & 7)] =
                        f2bf(fmaxf(acc[a2][nf][r], 0.0f));
                }
            }
    }
    {
        int nn = tid >> 4, c = tid & 15;
        *(short8*)&hw[nn * 136 + c * 8] = *(const short8*)(HWp + nn * 128 + c * 8);
    }
    __syncthreads();

    // ---- heads via MFMA: [mu|lv](128x16) = yd(128x128) @ HW^T ----
    if (wv) {
        f32x4 h0 = (f32x4)0.0f, h1 = (f32x4)0.0f;
        #pragma unroll
        for (int s2 = 0; s2 < 4; s2++) {
            const int slot = ((4 * s2 + q) ^ (m & 7)) * 8;
            short8 a0 = *(const short8*)&regionA[(w * 32 + m) * 128 + slot];
            short8 a1 = *(const short8*)&regionA[(w * 32 + 16 + m) * 128 + slot];
            short8 b  = *(const short8*)&hw[m * 136 + s2 * 32 + q * 8];
            h0 = __builtin_amdgcn_mfma_f32_16x16x32_bf16(a0, b, h0, 0, 0, 0);
            h1 = __builtin_amdgcn_mfma_f32_16x16x32_bf16(a1, b, h1, 0, 0, 0);
        }
        float hb = (m < 8) ? mub[m] : lvb[m - 8];
        #pragma unroll
        for (int r = 0; r < 4; r++) {
            mlv[(w * 32 + q * 4 + r) * 16 + m]      = h0[r] + hb;
            mlv[(w * 32 + 16 + q * 4 + r) * 16 + m] = h1[r] + hb;
        }
    }
    __syncthreads();

    // ---- per-node loss + segment sums ----
    float lsum = 0.0f;
    if (tid < 128 && bbase + tid < NN) {
        const int t = tid;
        const int n = bbase + t;
        const int op = op_id[n];
        const float4* w4 = (const float4*)(opwise + (size_t)op * 128);
        float mout[8], lout[8];
        #pragma unroll
        for (int k = 0; k < 8; k++) { mout[k] = 0.0f; lout[k] = 0.0f; }
        #pragma unroll
        for (int l = 0; l < 8; l++) {
            float mv = mlv[t * 16 + l];
            float vv = mlv[t * 16 + 8 + l];
            float4 a = w4[l * 4 + 0];
            float4 b = w4[l * 4 + 1];
            float4 c = w4[l * 4 + 2];
            float4 d = w4[l * 4 + 3];
            mout[0] = fmaf(mv, a.x, mout[0]); mout[1] = fmaf(mv, a.y, mout[1]);
            mout[2] = fmaf(mv, a.z, mout[2]); mout[3] = fmaf(mv, a.w, mout[3]);
            mout[4] = fmaf(mv, b.x, mout[4]); mout[5] = fmaf(mv, b.y, mout[5]);
            mout[6] = fmaf(mv, b.z, mout[6]); mout[7] = fmaf(mv, b.w, mout[7]);
            lout[0] = fmaf(vv, c.x, lout[0]); lout[1] = fmaf(vv, c.y, lout[1]);
            lout[2] = fmaf(vv, c.z, lout[2]); lout[3] = fmaf(vv, c.w, lout[3]);
            lout[4] = fmaf(vv, d.x, lout[4]); lout[5] = fmaf(vv, d.y, lout[5]);
            lout[6] = fmaf(vv, d.z, lout[6]); lout[7] = fmaf(vv, d.w, lout[7]);
        }
        const float4* lp = (const float4*)(lat + (size_t)n * 8);
        float4 lb0 = lp[0], lb1 = lp[1];
        float labels[8] = {lb0.x, lb0.y, lb0.z, lb0.w, lb1.x, lb1.y, lb1.z, lb1.w};
        float lnode = 0.0f;
        #pragma unroll
        for (int k = 0; k < 8; k++) {
            float diff = mout[k] - labels[k];
            lnode += diff * diff / (2.0f * expf(lout[k]) + 1e-7f) + 0.5f * lout[k];
        }
        lnode *= 0.125f;
        atomicAdd(&op_loss[op], lnode);
        atomicAdd(&op_cnt[op], 1.0f);
        lsum = lnode;
    }
    #pragma unroll
    for (int off = 32; off > 0; off >>= 1) lsum += __shfl_down(lsum, off);
    if (lane == 0) atomicAdd(loss_sum, lsum);
}

// ---------------- finalize ----------------
__global__ void final_kernel(const float* __restrict__ accum, float* __restrict__ out)
{
    out[0] = accum[1] / (float)NN - 0.5f * (accum[0] / (float)((size_t)NN * 128));
}

extern "C" void kernel_launch(void* const* d_in, const int* in_sizes, int n_in,
                              void* d_out, int out_size, void* d_ws, size_t ws_size,
                              hipStream_t stream) {
    const int*   op_id  = (const int*)  d_in[0];
    const int*   sv_id  = (const int*)  d_in[1];
    const int*   st_id  = (const int*)  d_in[2];
    const float* lat    = (const float*)d_in[3];
    const int*   esrc   = (const int*)  d_in[4];
    const int*   edst   = (const int*)  d_in[5];
    const float* eps    = (const float*)d_in[6];
    const float* opE    = (const float*)d_in[7];
    const float* svE    = (const float*)d_in[8];
    const float* stE    = (const float*)d_in[9];
    const float* W1     = (const float*)d_in[10];
    const float* b1     = (const float*)d_in[11];
    const float* W2     = (const float*)d_in[12];
    const float* b2     = (const float*)d_in[13];
    const float* Wself  = (const float*)d_in[14];
    const float* Wagg   = (const float*)d_in[15];
    const float* muW    = (const float*)d_in[16];
    const float* mub    = (const float*)d_in[17];
    const float* lvW    = (const float*)d_in[18];
    const float* lvb    = (const float*)d_in[19];
    const float* opwise = (const float*)d_in[20];

    char* wsb = (char*)d_ws;
    short* W1s      = (short*)(wsb + 0);              // 65536 B
    short* W2s      = (short*)(wsb + 65536);          // 65536 B
    short* Wds0     = (short*)(wsb + 131072);         // 32768 B
    short* Wds1     = (short*)(wsb + 163840);         // 32768 B
    short* HWp      = (short*)(wsb + 196608);         // 4096 B
    float* accum    = (float*)(wsb + 204800);         // 8 B: [0]=kl, [1]=loss
    int*   cnt      = (int*)  (wsb + (4  << 20));
    int*   rowstart = (int*)  (wsb + (6  << 20));
    int*   cursor   = (int*)  (wsb + (9  << 20));
    int*   csr      = (int*)  (wsb + (12 << 20));
    int*   bsum     = (int*)  (wsb + (16 << 20));
    short* h_bf     = (short*)(wsb + (32  << 20));    // 128 MB
    short* z_bf     = (short*)(wsb + (160ull << 20)); // 128 MB
    float* out      = (float*)d_out;

    hipMemsetAsync(d_out, 0, (size_t)out_size * sizeof(float), stream);
    hipMemsetAsync(accum, 0, 2 * sizeof(float), stream);
    hipMemsetAsync(cnt, 0, (size_t)NN * sizeof(int), stream);

    prep_kernel<<<128, 256, 0, stream>>>(W1, W2, Wself, Wagg, muW, lvW,
                                         W1s, W2s, Wds0, Wds1, HWp);

    hist_kernel<<<(NE + 255) / 256, 256, 0, stream>>>(edst, cnt);
    scan1_kernel<<<NBLK_SCAN, 256, 0, stream>>>(cnt, bsum);
    scan2_kernel<<<1, 512, 0, stream>>>(bsum, rowstart);
    scan3_kernel<<<NBLK_SCAN, 256, 0, stream>>>(cnt, bsum, rowstart, cursor);
    fill_kernel<<<(NE + 255) / 256, 256, 0, stream>>>(esrc, edst, cursor, csr);

    enc1_mfma<<<NBLK, 256, 0, stream>>>(op_id, sv_id, st_id, lat, opE, svE, stE, W1s, b1, h_bf);
    enc2_mfma<<<NBLK, 256, 0, stream>>>(h_bf, W2s, b2, eps, z_bf, accum + 0);
    dec_mfma<<<NBLK, 256, 0, stream>>>(z_bf, rowstart, csr, Wds0, Wds1, HWp, mub, lvb,
                                       opwise, op_id, lat,
                                       out + 1, out + 1 + OPC, accum + 1);
    final_kernel<<<1, 1, 0, stream>>>(accum, out);
}